// Round 1
// baseline (530.634 us; speedup 1.0000x reference)
//
#include <hip/hip_runtime.h>
#include <stdint.h>
#include <stddef.h>

#define L_SEQ 2048
#define NB 4
#define NH 16
#define HDIM 64
#define DMODEL 1024
#define ATT_SCALE 0.125f

typedef __attribute__((ext_vector_type(4))) float f32x4;
typedef __attribute__((ext_vector_type(8))) __bf16 bf16x8;
typedef __attribute__((ext_vector_type(4))) __bf16 bf16x4;

__device__ __forceinline__ void gload16(const void* g, void* l) {
  __builtin_amdgcn_global_load_lds((const __attribute__((address_space(1))) void*)g,
                                   (__attribute__((address_space(3))) void*)l, 16, 0, 0);
}

// ---------------- prep: x fp32 -> bf16 ----------------
__global__ void k_convert_x(const float* __restrict__ x, __bf16* __restrict__ xb) {
  int i = (blockIdx.x * 256 + threadIdx.x) * 4;
  float4 v = *(const float4*)(x + i);
  bf16x4 o;
  o[0] = (__bf16)v.x; o[1] = (__bf16)v.y; o[2] = (__bf16)v.z; o[3] = (__bf16)v.w;
  *(bf16x4*)(xb + i) = o;
}

// ---------------- prep: W (RxC fp32) -> Wt (CxR bf16) ----------------
__global__ void k_transpose_bf16(const float* __restrict__ W, __bf16* __restrict__ Wt,
                                 int R, int C) {
  __shared__ float t[32][33];
  int c0 = blockIdx.x * 32, r0 = blockIdx.y * 32;
  int tx = threadIdx.x, ty = threadIdx.y;  // 32 x 8
#pragma unroll
  for (int i = 0; i < 32; i += 8)
    t[ty + i][tx] = W[(size_t)(r0 + ty + i) * C + c0 + tx];
  __syncthreads();
#pragma unroll
  for (int i = 0; i < 32; i += 8)
    Wt[(size_t)(c0 + ty + i) * R + r0 + tx] = (__bf16)t[tx][ty + i];
}

// ---------------- m97-structure GEMM: C = A(MxK) * Bt(NxK)^T + bias ----------------
// EPI==0: scatter epilogue -> Q (scaled), K, V^T bf16 layouts for attention
// EPI==1: fp32 row-major output
template <int EPI>
__global__ __launch_bounds__(256, 2) void k_gemm(
    const __bf16* __restrict__ A, const __bf16* __restrict__ Bt,
    const float* __restrict__ bias, float* __restrict__ Cf,
    __bf16* __restrict__ Qo, __bf16* __restrict__ Ko, __bf16* __restrict__ Vto,
    int M, int N, int K) {
  __shared__ __bf16 As[128 * 32];
  __shared__ __bf16 Bs[128 * 32];
  const int tid = threadIdx.x;
  const int wave = tid >> 6, lane = tid & 63;
  const int brow = blockIdx.y * 128, bcol = blockIdx.x * 128;
  const int wr = wave >> 1, wc = wave & 1;
  const int g = lane >> 4, c16 = lane & 15;

  f32x4 acc[4][4] = {};

  const char* Ap = (const char*)(A + (size_t)(brow + wave * 16 + (lane >> 2)) * K) + (lane & 3) * 16;
  const char* Bp = (const char*)(Bt + (size_t)(bcol + wave * 16 + (lane >> 2)) * K) + (lane & 3) * 16;
  const size_t rowskip = (size_t)64 * K * 2;  // +64 rows in bytes
  char* AsW = (char*)As + wave * 1024;
  char* BsW = (char*)Bs + wave * 1024;

  for (int k0 = 0; k0 < K; k0 += 32) {
    gload16(Ap + (size_t)k0 * 2, AsW);
    gload16(Ap + (size_t)k0 * 2 + rowskip, AsW + 4096);
    gload16(Bp + (size_t)k0 * 2, BsW);
    gload16(Bp + (size_t)k0 * 2 + rowskip, BsW + 4096);
    __syncthreads();
    bf16x8 af[4], bfr[4];
#pragma unroll
    for (int m = 0; m < 4; ++m)
      af[m] = *(const bf16x8*)(As + (wr * 64 + m * 16 + c16) * 32 + g * 8);
#pragma unroll
    for (int n = 0; n < 4; ++n)
      bfr[n] = *(const bf16x8*)(Bs + (wc * 64 + n * 16 + c16) * 32 + g * 8);
#pragma unroll
    for (int m = 0; m < 4; ++m)
#pragma unroll
      for (int n = 0; n < 4; ++n)
        acc[m][n] = __builtin_amdgcn_mfma_f32_16x16x32_bf16(af[m], bfr[n], acc[m][n], 0, 0, 0);
    __syncthreads();
  }

#pragma unroll
  for (int m = 0; m < 4; ++m) {
#pragma unroll
    for (int n = 0; n < 4; ++n) {
      int gcol = bcol + wc * 64 + n * 16 + c16;
      float bv = bias[gcol];
#pragma unroll
      for (int r = 0; r < 4; ++r) {
        int grow = brow + wr * 64 + m * 16 + g * 4 + r;
        float v = acc[m][n][r] + bv;
        if (EPI == 0) {
          int which = gcol >> 10, hh = (gcol >> 6) & 15, d = gcol & 63;
          int b = grow >> 11, l = grow & 2047;
          size_t bh = (size_t)b * NH + hh;
          if (which == 0)
            Qo[(bh * L_SEQ + l) * HDIM + d] = (__bf16)(v * ATT_SCALE);
          else if (which == 1)
            Ko[(bh * L_SEQ + l) * HDIM + d] = (__bf16)v;
          else
            Vto[(bh * HDIM + d) * L_SEQ + l] = (__bf16)v;
        } else {
          Cf[(size_t)grow * N + gcol] = v;
        }
      }
    }
  }
}

// ---------------- flash attention: per block one (b,h) x 128 Q rows ----------------
__global__ __launch_bounds__(256, 2) void k_attn(
    const __bf16* __restrict__ Q, const __bf16* __restrict__ K,
    const __bf16* __restrict__ Vt, __bf16* __restrict__ O) {
  __shared__ __bf16 Pl[4][32 * 64];  // per-wave P tile, XOR-swizzled rows of 128B
  const int bh = blockIdx.y;
  const int q0 = blockIdx.x * 128;
  const int wave = threadIdx.x >> 6, lane = threadIdx.x & 63;
  const int g = lane >> 4, c = lane & 15;
  const int qw = q0 + wave * 32;
  const __bf16* Qb = Q + (size_t)bh * L_SEQ * HDIM;
  const __bf16* Kb = K + (size_t)bh * L_SEQ * HDIM;
  const __bf16* Vb = Vt + (size_t)bh * HDIM * L_SEQ;

  // Q fragments held in registers for the whole kernel
  bf16x8 qf[2][2];
#pragma unroll
  for (int m = 0; m < 2; ++m)
#pragma unroll
    for (int kc = 0; kc < 2; ++kc)
      qf[m][kc] = *(const bf16x8*)(Qb + (size_t)(qw + m * 16 + c) * HDIM + kc * 32 + g * 8);

  f32x4 o[2][4] = {};
  float mrun[2][4], lrun[2][4];
#pragma unroll
  for (int m = 0; m < 2; ++m)
#pragma unroll
    for (int r = 0; r < 4; ++r) { mrun[m][r] = -1e30f; lrun[m][r] = 0.f; }

  char* P = (char*)Pl[wave];

  for (int kv0 = 0; kv0 < L_SEQ; kv0 += 64) {
    // S = Q * K^T  (Q pre-scaled by 1/sqrt(d) in GEMM1 epilogue)
    f32x4 s[2][4] = {};
#pragma unroll
    for (int kc = 0; kc < 2; ++kc) {
      bf16x8 kf[4];
#pragma unroll
      for (int n = 0; n < 4; ++n)
        kf[n] = *(const bf16x8*)(Kb + (size_t)(kv0 + n * 16 + c) * HDIM + kc * 32 + g * 8);
#pragma unroll
      for (int m = 0; m < 2; ++m)
#pragma unroll
        for (int n = 0; n < 4; ++n)
          s[m][n] = __builtin_amdgcn_mfma_f32_16x16x32_bf16(qf[m][kc], kf[n], s[m][n], 0, 0, 0);
    }
    // online softmax per row (row lives in 16-lane group, 4 regs per lane across n)
#pragma unroll
    for (int m = 0; m < 2; ++m) {
#pragma unroll
      for (int r = 0; r < 4; ++r) {
        float v0 = s[m][0][r], v1 = s[m][1][r], v2 = s[m][2][r], v3 = s[m][3][r];
        float mx = fmaxf(fmaxf(v0, v1), fmaxf(v2, v3));
        mx = fmaxf(mx, __shfl_xor(mx, 1, 64));
        mx = fmaxf(mx, __shfl_xor(mx, 2, 64));
        mx = fmaxf(mx, __shfl_xor(mx, 4, 64));
        mx = fmaxf(mx, __shfl_xor(mx, 8, 64));
        float mnew = fmaxf(mrun[m][r], mx);
        float corr = __expf(mrun[m][r] - mnew);
        mrun[m][r] = mnew;
        float p0 = __expf(v0 - mnew), p1 = __expf(v1 - mnew);
        float p2 = __expf(v2 - mnew), p3 = __expf(v3 - mnew);
        float ps = (p0 + p1) + (p2 + p3);
        ps += __shfl_xor(ps, 1, 64);
        ps += __shfl_xor(ps, 2, 64);
        ps += __shfl_xor(ps, 4, 64);
        ps += __shfl_xor(ps, 8, 64);
        lrun[m][r] = lrun[m][r] * corr + ps;
#pragma unroll
        for (int dn = 0; dn < 4; ++dn) o[m][dn][r] *= corr;
        int row = m * 16 + g * 4 + r;
        int sw = (row & 7) << 4;
        char* Prow = P + row * 128;
        *(__bf16*)(Prow + (((0 * 16 + c) * 2) ^ sw)) = (__bf16)p0;
        *(__bf16*)(Prow + (((1 * 16 + c) * 2) ^ sw)) = (__bf16)p1;
        *(__bf16*)(Prow + (((2 * 16 + c) * 2) ^ sw)) = (__bf16)p2;
        *(__bf16*)(Prow + (((3 * 16 + c) * 2) ^ sw)) = (__bf16)p3;
      }
    }
    __syncthreads();
    // O += P * V   (A = P from swizzled LDS, B = V^T rows from global)
#pragma unroll
    for (int kc = 0; kc < 2; ++kc) {
      bf16x8 pf[2];
#pragma unroll
      for (int m = 0; m < 2; ++m) {
        int row = m * 16 + c;
        int off = (row * 128 + kc * 64 + g * 16) ^ ((row & 7) << 4);
        pf[m] = *(const bf16x8*)(P + off);
      }
#pragma unroll
      for (int dn = 0; dn < 4; ++dn) {
        bf16x8 vf = *(const bf16x8*)(Vb + (size_t)(dn * 16 + c) * L_SEQ + kv0 + kc * 32 + g * 8);
#pragma unroll
        for (int m = 0; m < 2; ++m)
          o[m][dn] = __builtin_amdgcn_mfma_f32_16x16x32_bf16(pf[m], vf, o[m][dn], 0, 0, 0);
      }
    }
    __syncthreads();
  }

  // normalize + write O as [B, L, H*64] bf16
  const int b = bh >> 4, h = bh & 15;
#pragma unroll
  for (int m = 0; m < 2; ++m) {
#pragma unroll
    for (int r = 0; r < 4; ++r) {
      float inv = 1.f / lrun[m][r];
      int l = qw + m * 16 + g * 4 + r;
#pragma unroll
      for (int dn = 0; dn < 4; ++dn)
        O[((size_t)b * L_SEQ + l) * DMODEL + h * 64 + dn * 16 + c] = (__bf16)(o[m][dn][r] * inv);
    }
  }
}

extern "C" void kernel_launch(void* const* d_in, const int* in_sizes, int n_in,
                              void* d_out, int out_size, void* d_ws, size_t ws_size,
                              hipStream_t stream) {
  const float* x = (const float*)d_in[0];
  const float* Wqkv = (const float*)d_in[1];
  const float* bqkv = (const float*)d_in[2];
  const float* Wout = (const float*)d_in[3];
  const float* bout = (const float*)d_in[4];
  float* out = (float*)d_out;

  char* ws = (char*)d_ws;
  // layout (bytes): Xb 16MB | Wqkvt 6MB | Woutt 2MB | Q 16MB | K 16MB | Vt 16MB ; O reuses Xb
  __bf16* Xb    = (__bf16*)(ws + 0);
  __bf16* Wqkvt = (__bf16*)(ws + 16777216);
  __bf16* Woutt = (__bf16*)(ws + 23068672);
  __bf16* Qb    = (__bf16*)(ws + 25165824);
  __bf16* Kb    = (__bf16*)(ws + 41943040);
  __bf16* Vtb   = (__bf16*)(ws + 58720256);
  __bf16* Ob    = (__bf16*)(ws + 0);  // reuse Xb region after GEMM1

  k_convert_x<<<8192, 256, 0, stream>>>(x, Xb);
  k_transpose_bf16<<<dim3(96, 32), dim3(32, 8), 0, stream>>>(Wqkv, Wqkvt, 1024, 3072);
  k_transpose_bf16<<<dim3(32, 32), dim3(32, 8), 0, stream>>>(Wout, Woutt, 1024, 1024);
  // QKV projection: M=8192, N=3072, K=1024
  k_gemm<0><<<dim3(24, 64), 256, 0, stream>>>(Xb, Wqkvt, bqkv, nullptr, Qb, Kb, Vtb,
                                              8192, 3072, 1024);
  // attention: 16 q-tiles x 64 (b,h)
  k_attn<<<dim3(16, 64), 256, 0, stream>>>(Qb, Kb, Vtb, Ob);
  // output projection: M=8192, N=1024, K=1024
  k_gemm<1><<<dim3(8, 64), 256, 0, stream>>>(Ob, Woutt, bout, out, nullptr, nullptr, nullptr,
                                             8192, 1024, 1024);
}

// Round 2
// 420.658 us; speedup vs baseline: 1.2614x; 1.2614x over previous
//
#include <hip/hip_runtime.h>
#include <stdint.h>
#include <stddef.h>

#define L_SEQ 2048
#define NB 4
#define NH 16
#define HDIM 64
#define DMODEL 1024
#define ATT_SCALE 0.125f

typedef __attribute__((ext_vector_type(4))) float f32x4;
typedef __attribute__((ext_vector_type(16))) float f32x16;
typedef __attribute__((ext_vector_type(8))) __bf16 bf16x8;
typedef __attribute__((ext_vector_type(4))) __bf16 bf16x4;

__device__ __forceinline__ void gload16(const void* g, void* l) {
  __builtin_amdgcn_global_load_lds((const __attribute__((address_space(1))) void*)g,
                                   (__attribute__((address_space(3))) void*)l, 16, 0, 0);
}

// ---------------- prep: x fp32 -> bf16 ----------------
__global__ void k_convert_x(const float* __restrict__ x, __bf16* __restrict__ xb) {
  int i = (blockIdx.x * 256 + threadIdx.x) * 4;
  float4 v = *(const float4*)(x + i);
  bf16x4 o;
  o[0] = (__bf16)v.x; o[1] = (__bf16)v.y; o[2] = (__bf16)v.z; o[3] = (__bf16)v.w;
  *(bf16x4*)(xb + i) = o;
}

// ---------------- prep: W (RxC fp32) -> Wt (CxR bf16) ----------------
__global__ void k_transpose_bf16(const float* __restrict__ W, __bf16* __restrict__ Wt,
                                 int R, int C) {
  __shared__ float t[32][33];
  int c0 = blockIdx.x * 32, r0 = blockIdx.y * 32;
  int tx = threadIdx.x, ty = threadIdx.y;  // 32 x 8
#pragma unroll
  for (int i = 0; i < 32; i += 8)
    t[ty + i][tx] = W[(size_t)(r0 + ty + i) * C + c0 + tx];
  __syncthreads();
#pragma unroll
  for (int i = 0; i < 32; i += 8)
    Wt[(size_t)(c0 + ty + i) * R + r0 + tx] = (__bf16)t[tx][ty + i];
}

// ---------------- m97-structure GEMM: C = A(MxK) * Bt(NxK)^T + bias ----------------
template <int EPI>
__global__ __launch_bounds__(256, 2) void k_gemm(
    const __bf16* __restrict__ A, const __bf16* __restrict__ Bt,
    const float* __restrict__ bias, float* __restrict__ Cf,
    __bf16* __restrict__ Qo, __bf16* __restrict__ Ko, __bf16* __restrict__ Vto,
    int M, int N, int K) {
  __shared__ __bf16 As[128 * 32];
  __shared__ __bf16 Bs[128 * 32];
  const int tid = threadIdx.x;
  const int wave = tid >> 6, lane = tid & 63;
  const int brow = blockIdx.y * 128, bcol = blockIdx.x * 128;
  const int wr = wave >> 1, wc = wave & 1;
  const int g = lane >> 4, c16 = lane & 15;

  f32x4 acc[4][4] = {};

  const char* Ap = (const char*)(A + (size_t)(brow + wave * 16 + (lane >> 2)) * K) + (lane & 3) * 16;
  const char* Bp = (const char*)(Bt + (size_t)(bcol + wave * 16 + (lane >> 2)) * K) + (lane & 3) * 16;
  const size_t rowskip = (size_t)64 * K * 2;  // +64 rows in bytes
  char* AsW = (char*)As + wave * 1024;
  char* BsW = (char*)Bs + wave * 1024;

  for (int k0 = 0; k0 < K; k0 += 32) {
    gload16(Ap + (size_t)k0 * 2, AsW);
    gload16(Ap + (size_t)k0 * 2 + rowskip, AsW + 4096);
    gload16(Bp + (size_t)k0 * 2, BsW);
    gload16(Bp + (size_t)k0 * 2 + rowskip, BsW + 4096);
    __syncthreads();
    bf16x8 af[4], bfr[4];
#pragma unroll
    for (int m = 0; m < 4; ++m)
      af[m] = *(const bf16x8*)(As + (wr * 64 + m * 16 + c16) * 32 + g * 8);
#pragma unroll
    for (int n = 0; n < 4; ++n)
      bfr[n] = *(const bf16x8*)(Bs + (wc * 64 + n * 16 + c16) * 32 + g * 8);
#pragma unroll
    for (int m = 0; m < 4; ++m)
#pragma unroll
      for (int n = 0; n < 4; ++n)
        acc[m][n] = __builtin_amdgcn_mfma_f32_16x16x32_bf16(af[m], bfr[n], acc[m][n], 0, 0, 0);
    __syncthreads();
  }

#pragma unroll
  for (int m = 0; m < 4; ++m) {
#pragma unroll
    for (int n = 0; n < 4; ++n) {
      int gcol = bcol + wc * 64 + n * 16 + c16;
      float bv = bias[gcol];
#pragma unroll
      for (int r = 0; r < 4; ++r) {
        int grow = brow + wr * 64 + m * 16 + g * 4 + r;
        float v = acc[m][n][r] + bv;
        if (EPI == 0) {
          int which = gcol >> 10, hh = (gcol >> 6) & 15, d = gcol & 63;
          int b = grow >> 11, l = grow & 2047;
          size_t bh = (size_t)b * NH + hh;
          if (which == 0)
            Qo[(bh * L_SEQ + l) * HDIM + d] = (__bf16)(v * ATT_SCALE);
          else if (which == 1)
            Ko[(bh * L_SEQ + l) * HDIM + d] = (__bf16)v;
          else
            Vto[(bh * HDIM + d) * L_SEQ + l] = (__bf16)v;
        } else {
          Cf[(size_t)grow * N + gcol] = v;
        }
      }
    }
  }
}

// ---------------- helpers for in-register softmax / P relayout ----------------
__device__ __forceinline__ int cvtpk(float a, float b) {
  int r;
  asm("v_cvt_pk_bf16_f32 %0, %1, %2" : "=v"(r) : "v"(a), "v"(b));
  return r;
}
__device__ __forceinline__ void pswap(int& a, int& b) {
  asm("v_permlane32_swap_b32 %0, %1" : "+v"(a), "+v"(b));
}
// Build PV A-fragment (kv = base + hi*8 + j) from 8 in-lane P values
// p0..p3: own kv {0..3}(+4hi-adjusted), p4..p7: kv {8..11} family; see C/D layout.
__device__ __forceinline__ bf16x8 make_pa(float p0, float p1, float p2, float p3,
                                          float p4, float p5, float p6, float p7) {
  int a0 = cvtpk(p0, p1);
  int a1 = cvtpk(p2, p3);
  int b0 = cvtpk(p4, p5);
  int b1 = cvtpk(p6, p7);
  pswap(a0, b0);  // a0 -> {j0,j1}, b0 -> {j4,j5}
  pswap(a1, b1);  // a1 -> {j2,j3}, b1 -> {j6,j7}
  union { int i[4]; bf16x8 v; } u;
  u.i[0] = a0; u.i[1] = a1; u.i[2] = b0; u.i[3] = b1;
  return u.v;
}

// ---------------- flash attention: 32x32 swapped-QK^T, barrier-free ----------------
// One wave owns 32 q-rows; lane owns ONE q-row (q = lane&31); partner lane^32
// holds the complementary kv-halves. KVBLK=64 (two 32x32 S-tiles per iter).
__global__ __launch_bounds__(256) void k_attn(
    const __bf16* __restrict__ Q, const __bf16* __restrict__ K,
    const __bf16* __restrict__ Vt, __bf16* __restrict__ O) {
  const int bh = blockIdx.y;
  const int wave = threadIdx.x >> 6, lane = threadIdx.x & 63;
  const int r31 = lane & 31, hi = lane >> 5;
  const int qw = blockIdx.x * 128 + wave * 32;
  const __bf16* Qb = Q + (size_t)bh * L_SEQ * HDIM;
  const __bf16* Kb = K + (size_t)bh * L_SEQ * HDIM;
  const __bf16* Vb = Vt + (size_t)bh * HDIM * L_SEQ;

  // Q fragments (B-operand): q = lane&31, hdim slice kc*16 + hi*8 + {0..7}
  bf16x8 qf[4];
#pragma unroll
  for (int kc = 0; kc < 4; ++kc)
    qf[kc] = *(const bf16x8*)(Qb + (size_t)(qw + r31) * HDIM + kc * 16 + hi * 8);

  f32x16 o0 = {}, o1 = {};           // O accum, d-tiles 0/1 (col = lane&31 (+32))
  float m = -1e30f, l = 0.f;         // per-lane row state (row q = lane&31)

  for (int kv0 = 0; kv0 < L_SEQ; kv0 += 64) {
    // K fragments (A-operand): kv row = kv0 + t*32 + (lane&31)
    bf16x8 kf0[4], kf1[4];
#pragma unroll
    for (int kc = 0; kc < 4; ++kc) {
      kf0[kc] = *(const bf16x8*)(Kb + (size_t)(kv0 + r31) * HDIM + kc * 16 + hi * 8);
      kf1[kc] = *(const bf16x8*)(Kb + (size_t)(kv0 + 32 + r31) * HDIM + kc * 16 + hi * 8);
    }
    // V fragments (B-operand): row d = dt*32 + (lane&31), kv slice contiguous
    bf16x8 vf[2][2][2];  // [t][h2][dt]
#pragma unroll
    for (int t = 0; t < 2; ++t)
#pragma unroll
      for (int h2 = 0; h2 < 2; ++h2)
#pragma unroll
        for (int dt = 0; dt < 2; ++dt)
          vf[t][h2][dt] = *(const bf16x8*)(Vb + (size_t)(dt * 32 + r31) * L_SEQ +
                                           kv0 + t * 32 + h2 * 16 + hi * 8);

    // S^T = K · Q^T  ->  D[kv][q]: col = q = lane&31, rows = kv per reg
    f32x16 s0 = {}, s1 = {};
#pragma unroll
    for (int kc = 0; kc < 4; ++kc) {
      s0 = __builtin_amdgcn_mfma_f32_32x32x16_bf16(kf0[kc], qf[kc], s0, 0, 0, 0);
      s1 = __builtin_amdgcn_mfma_f32_32x32x16_bf16(kf1[kc], qf[kc], s1, 0, 0, 0);
    }

    // ---- in-register online softmax (lane owns one q-row) ----
    float t8[8];
#pragma unroll
    for (int i = 0; i < 8; ++i)
      t8[i] = fmaxf(fmaxf(s0[i], s0[i + 8]), fmaxf(s1[i], s1[i + 8]));
#pragma unroll
    for (int i = 0; i < 4; ++i) t8[i] = fmaxf(t8[i], t8[i + 4]);
    float mx = fmaxf(fmaxf(t8[0], t8[1]), fmaxf(t8[2], t8[3]));
    mx = fmaxf(mx, __shfl_xor(mx, 32, 64));  // other kv-half from partner lane

    if (__any(mx > m + 8.f)) {               // defer-max (T13)
      float mnew = fmaxf(m, mx);
      float corr = __expf(m - mnew);
      l *= corr;
#pragma unroll
      for (int i = 0; i < 16; ++i) { o0[i] *= corr; o1[i] *= corr; }
      m = mnew;
    }
#pragma unroll
    for (int i = 0; i < 16; ++i) {
      s0[i] = __expf(s0[i] - m);
      s1[i] = __expf(s1[i] - m);
    }
    float a8[8];
#pragma unroll
    for (int i = 0; i < 8; ++i)
      a8[i] = (s0[i] + s0[i + 8]) + (s1[i] + s1[i + 8]);
#pragma unroll
    for (int i = 0; i < 4; ++i) a8[i] += a8[i + 4];
    float ps = (a8[0] + a8[1]) + (a8[2] + a8[3]);
    ps += __shfl_xor(ps, 32, 64);
    l += ps;

    // ---- P -> bf16 A-fragments (T12) and PV ----
    bf16x8 pa;
    pa = make_pa(s0[0], s0[1], s0[2], s0[3], s0[4], s0[5], s0[6], s0[7]);
    o0 = __builtin_amdgcn_mfma_f32_32x32x16_bf16(pa, vf[0][0][0], o0, 0, 0, 0);
    o1 = __builtin_amdgcn_mfma_f32_32x32x16_bf16(pa, vf[0][0][1], o1, 0, 0, 0);
    pa = make_pa(s0[8], s0[9], s0[10], s0[11], s0[12], s0[13], s0[14], s0[15]);
    o0 = __builtin_amdgcn_mfma_f32_32x32x16_bf16(pa, vf[0][1][0], o0, 0, 0, 0);
    o1 = __builtin_amdgcn_mfma_f32_32x32x16_bf16(pa, vf[0][1][1], o1, 0, 0, 0);
    pa = make_pa(s1[0], s1[1], s1[2], s1[3], s1[4], s1[5], s1[6], s1[7]);
    o0 = __builtin_amdgcn_mfma_f32_32x32x16_bf16(pa, vf[1][0][0], o0, 0, 0, 0);
    o1 = __builtin_amdgcn_mfma_f32_32x32x16_bf16(pa, vf[1][0][1], o1, 0, 0, 0);
    pa = make_pa(s1[8], s1[9], s1[10], s1[11], s1[12], s1[13], s1[14], s1[15]);
    o0 = __builtin_amdgcn_mfma_f32_32x32x16_bf16(pa, vf[1][1][0], o0, 0, 0, 0);
    o1 = __builtin_amdgcn_mfma_f32_32x32x16_bf16(pa, vf[1][1][1], o1, 0, 0, 0);
  }

  // ---- normalize + store: lane holds (q per reg, d = lane&31 (+32)) ----
  const int b = bh >> 4, h = bh & 15;
  float linv = 1.f / l;
#pragma unroll
  for (int r = 0; r < 16; ++r) {
    int ql = (r & 3) + 8 * (r >> 2) + 4 * hi;
    float li = __shfl(linv, ql, 64);
    size_t base = ((size_t)b * L_SEQ + qw + ql) * DMODEL + h * 64 + r31;
    O[base] = (__bf16)(o0[r] * li);
    O[base + 32] = (__bf16)(o1[r] * li);
  }
}

extern "C" void kernel_launch(void* const* d_in, const int* in_sizes, int n_in,
                              void* d_out, int out_size, void* d_ws, size_t ws_size,
                              hipStream_t stream) {
  const float* x = (const float*)d_in[0];
  const float* Wqkv = (const float*)d_in[1];
  const float* bqkv = (const float*)d_in[2];
  const float* Wout = (const float*)d_in[3];
  const float* bout = (const float*)d_in[4];
  float* out = (float*)d_out;

  char* ws = (char*)d_ws;
  __bf16* Xb    = (__bf16*)(ws + 0);
  __bf16* Wqkvt = (__bf16*)(ws + 16777216);
  __bf16* Woutt = (__bf16*)(ws + 23068672);
  __bf16* Qb    = (__bf16*)(ws + 25165824);
  __bf16* Kb    = (__bf16*)(ws + 41943040);
  __bf16* Vtb   = (__bf16*)(ws + 58720256);
  __bf16* Ob    = (__bf16*)(ws + 0);  // reuse Xb region after GEMM1

  k_convert_x<<<8192, 256, 0, stream>>>(x, Xb);
  k_transpose_bf16<<<dim3(96, 32), dim3(32, 8), 0, stream>>>(Wqkv, Wqkvt, 1024, 3072);
  k_transpose_bf16<<<dim3(32, 32), dim3(32, 8), 0, stream>>>(Wout, Woutt, 1024, 1024);
  k_gemm<0><<<dim3(24, 64), 256, 0, stream>>>(Xb, Wqkvt, bqkv, nullptr, Qb, Kb, Vtb,
                                              8192, 3072, 1024);
  k_attn<<<dim3(16, 64), 256, 0, stream>>>(Qb, Kb, Vtb, Ob);
  k_gemm<1><<<dim3(8, 64), 256, 0, stream>>>(Ob, Woutt, bout, out, nullptr, nullptr, nullptr,
                                             8192, 1024, 1024);
}

// Round 3
// 365.083 us; speedup vs baseline: 1.4535x; 1.1522x over previous
//
#include <hip/hip_runtime.h>
#include <stdint.h>
#include <stddef.h>

#define L_SEQ 2048
#define NB 4
#define NH 16
#define HDIM 64
#define DMODEL 1024
// 1/sqrt(64) * log2(e): softmax computed in exp2 domain
#define ATT_SCALE_L2E 0.1803368801f

typedef __attribute__((ext_vector_type(4))) float f32x4;
typedef __attribute__((ext_vector_type(16))) float f32x16;
typedef __attribute__((ext_vector_type(8))) __bf16 bf16x8;
typedef __attribute__((ext_vector_type(4))) __bf16 bf16x4;

__device__ __forceinline__ void gload16(const void* g, void* l) {
  __builtin_amdgcn_global_load_lds((const __attribute__((address_space(1))) void*)g,
                                   (__attribute__((address_space(3))) void*)l, 16, 0, 0);
}

// ---------------- prep: x fp32 -> bf16 ----------------
__global__ void k_convert_x(const float* __restrict__ x, __bf16* __restrict__ xb) {
  int i = (blockIdx.x * 256 + threadIdx.x) * 4;
  float4 v = *(const float4*)(x + i);
  bf16x4 o;
  o[0] = (__bf16)v.x; o[1] = (__bf16)v.y; o[2] = (__bf16)v.z; o[3] = (__bf16)v.w;
  *(bf16x4*)(xb + i) = o;
}

// ---------------- prep: W (RxC fp32) -> Wt (CxR bf16) ----------------
__global__ void k_transpose_bf16(const float* __restrict__ W, __bf16* __restrict__ Wt,
                                 int R, int C) {
  __shared__ float t[32][33];
  int c0 = blockIdx.x * 32, r0 = blockIdx.y * 32;
  int tx = threadIdx.x, ty = threadIdx.y;  // 32 x 8
#pragma unroll
  for (int i = 0; i < 32; i += 8)
    t[ty + i][tx] = W[(size_t)(r0 + ty + i) * C + c0 + tx];
  __syncthreads();
#pragma unroll
  for (int i = 0; i < 32; i += 8)
    Wt[(size_t)(c0 + ty + i) * R + r0 + tx] = (__bf16)t[tx][ty + i];
}

// ---------------- m97-structure GEMM: C = A(MxK) * Bt(NxK)^T + bias ----------------
template <int EPI>
__global__ __launch_bounds__(256, 2) void k_gemm(
    const __bf16* __restrict__ A, const __bf16* __restrict__ Bt,
    const float* __restrict__ bias, float* __restrict__ Cf,
    __bf16* __restrict__ Qo, __bf16* __restrict__ Ko, __bf16* __restrict__ Vto,
    int M, int N, int K) {
  __shared__ __bf16 As[128 * 32];
  __shared__ __bf16 Bs[128 * 32];
  const int tid = threadIdx.x;
  const int wave = tid >> 6, lane = tid & 63;
  const int brow = blockIdx.y * 128, bcol = blockIdx.x * 128;
  const int wr = wave >> 1, wc = wave & 1;
  const int g = lane >> 4, c16 = lane & 15;

  f32x4 acc[4][4] = {};

  const char* Ap = (const char*)(A + (size_t)(brow + wave * 16 + (lane >> 2)) * K) + (lane & 3) * 16;
  const char* Bp = (const char*)(Bt + (size_t)(bcol + wave * 16 + (lane >> 2)) * K) + (lane & 3) * 16;
  const size_t rowskip = (size_t)64 * K * 2;
  char* AsW = (char*)As + wave * 1024;
  char* BsW = (char*)Bs + wave * 1024;

  for (int k0 = 0; k0 < K; k0 += 32) {
    gload16(Ap + (size_t)k0 * 2, AsW);
    gload16(Ap + (size_t)k0 * 2 + rowskip, AsW + 4096);
    gload16(Bp + (size_t)k0 * 2, BsW);
    gload16(Bp + (size_t)k0 * 2 + rowskip, BsW + 4096);
    __syncthreads();
    bf16x8 af[4], bfr[4];
#pragma unroll
    for (int m = 0; m < 4; ++m)
      af[m] = *(const bf16x8*)(As + (wr * 64 + m * 16 + c16) * 32 + g * 8);
#pragma unroll
    for (int n = 0; n < 4; ++n)
      bfr[n] = *(const bf16x8*)(Bs + (wc * 64 + n * 16 + c16) * 32 + g * 8);
#pragma unroll
    for (int m = 0; m < 4; ++m)
#pragma unroll
      for (int n = 0; n < 4; ++n)
        acc[m][n] = __builtin_amdgcn_mfma_f32_16x16x32_bf16(af[m], bfr[n], acc[m][n], 0, 0, 0);
    __syncthreads();
  }

#pragma unroll
  for (int m = 0; m < 4; ++m) {
#pragma unroll
    for (int n = 0; n < 4; ++n) {
      int gcol = bcol + wc * 64 + n * 16 + c16;
      float bv = bias[gcol];
#pragma unroll
      for (int r = 0; r < 4; ++r) {
        int grow = brow + wr * 64 + m * 16 + g * 4 + r;
        float v = acc[m][n][r] + bv;
        if (EPI == 0) {
          int which = gcol >> 10, hh = (gcol >> 6) & 15, d = gcol & 63;
          int b = grow >> 11, l = grow & 2047;
          size_t bh = (size_t)b * NH + hh;
          if (which == 0)
            Qo[(bh * L_SEQ + l) * HDIM + d] = (__bf16)(v * ATT_SCALE_L2E);
          else if (which == 1)
            Ko[(bh * L_SEQ + l) * HDIM + d] = (__bf16)v;
          else
            Vto[(bh * HDIM + d) * L_SEQ + l] = (__bf16)v;
        } else {
          Cf[(size_t)grow * N + gcol] = v;
        }
      }
    }
  }
}

// ---------------- helpers ----------------
__device__ __forceinline__ float fexp2(float x) {
  float r;
  asm("v_exp_f32 %0, %1" : "=v"(r) : "v"(x));
  return r;
}
__device__ __forceinline__ int cvtpk(float a, float b) {
  int r;
  asm("v_cvt_pk_bf16_f32 %0, %1, %2" : "=v"(r) : "v"(a), "v"(b));
  return r;
}
__device__ __forceinline__ void pswap(int& a, int& b) {
  asm("v_permlane32_swap_b32 %0, %1" : "+v"(a), "+v"(b));
}
// Build PV A-fragment from 8 in-lane P values (verified round 1/2)
__device__ __forceinline__ bf16x8 make_pa(float p0, float p1, float p2, float p3,
                                          float p4, float p5, float p6, float p7) {
  int a0 = cvtpk(p0, p1);
  int a1 = cvtpk(p2, p3);
  int b0 = cvtpk(p4, p5);
  int b1 = cvtpk(p6, p7);
  pswap(a0, b0);
  pswap(a1, b1);
  union { int i[4]; bf16x8 v; } u;
  u.i[0] = a0; u.i[1] = a1; u.i[2] = b0; u.i[3] = b1;
  return u.v;
}

// ---------------- flash attention: KVBLK=32, K-prefetch pipeline, XCD swizzle ----
// Wave owns 32 q-rows; lane owns one q-row (q = lane&31); exp2-domain softmax.
__global__ __launch_bounds__(256, 3) void k_attn(
    const __bf16* __restrict__ Q, const __bf16* __restrict__ K,
    const __bf16* __restrict__ Vt, __bf16* __restrict__ O) {
  // XCD-aware decode: all 16 q-tiles of a head on one XCD (8 heads/XCD -> 4MB L2)
  const int blk = blockIdx.x;                    // 0..1023, XCD = blk & 7
  const int idx = (blk & 7) * 128 + (blk >> 3);  // bijective
  const int bh = idx >> 4;
  const int qt = idx & 15;
  const int wave = threadIdx.x >> 6, lane = threadIdx.x & 63;
  const int r31 = lane & 31, hi = lane >> 5;
  const int qw = qt * 128 + wave * 32;
  const __bf16* Qb = Q + (size_t)bh * L_SEQ * HDIM;
  const __bf16* Kb = K + (size_t)bh * L_SEQ * HDIM;
  const __bf16* Vb = Vt + (size_t)bh * HDIM * L_SEQ;

  // Q fragments (B-operand): q = lane&31, hdim slice kc*16 + hi*8 + {0..7}
  bf16x8 qf[4];
#pragma unroll
  for (int kc = 0; kc < 4; ++kc)
    qf[kc] = *(const bf16x8*)(Qb + (size_t)(qw + r31) * HDIM + kc * 16 + hi * 8);

  f32x16 o0 = {}, o1 = {};  // O accum: row=q (reg-mapped), col d = lane&31 (+32)
  float m = -1e30f, l = 0.f;

#define LOADK(dst, kvb) do {                                          \
    const __bf16* kp_ = Kb + (size_t)((kvb) + r31) * HDIM + hi * 8;   \
    dst[0] = *(const bf16x8*)(kp_);                                   \
    dst[1] = *(const bf16x8*)(kp_ + 16);                              \
    dst[2] = *(const bf16x8*)(kp_ + 32);                              \
    dst[3] = *(const bf16x8*)(kp_ + 48);                              \
  } while (0)

#define LOADV(dst, kvb) do {                                          \
    const __bf16* vp_ = Vb + (size_t)r31 * L_SEQ + (kvb) + hi * 8;    \
    dst[0][0] = *(const bf16x8*)(vp_);                                \
    dst[1][0] = *(const bf16x8*)(vp_ + 16);                           \
    dst[0][1] = *(const bf16x8*)(vp_ + 32 * L_SEQ);                   \
    dst[1][1] = *(const bf16x8*)(vp_ + 32 * L_SEQ + 16);              \
  } while (0)

#define BODY(kf, vf) do {                                                          \
    f32x16 s = {};                                                                 \
    _Pragma("unroll")                                                              \
    for (int kc = 0; kc < 4; ++kc)                                                 \
      s = __builtin_amdgcn_mfma_f32_32x32x16_bf16(kf[kc], qf[kc], s, 0, 0, 0);     \
    float t8[8];                                                                   \
    _Pragma("unroll") for (int i = 0; i < 8; ++i) t8[i] = fmaxf(s[i], s[i + 8]);   \
    _Pragma("unroll") for (int i = 0; i < 4; ++i) t8[i] = fmaxf(t8[i], t8[i + 4]); \
    float mx = fmaxf(fmaxf(t8[0], t8[1]), fmaxf(t8[2], t8[3]));                    \
    mx = fmaxf(mx, __shfl_xor(mx, 32, 64));                                        \
    if (__any(mx > m + 12.f)) {                                                    \
      float mnew = fmaxf(m, mx);                                                   \
      float corr = fexp2(m - mnew);                                                \
      l *= corr;                                                                   \
      _Pragma("unroll") for (int i = 0; i < 16; ++i) { o0[i] *= corr; o1[i] *= corr; } \
      m = mnew;                                                                    \
    }                                                                              \
    _Pragma("unroll") for (int i = 0; i < 16; ++i) s[i] = fexp2(s[i] - m);         \
    float a8[8];                                                                   \
    _Pragma("unroll") for (int i = 0; i < 8; ++i) a8[i] = s[i] + s[i + 8];         \
    _Pragma("unroll") for (int i = 0; i < 4; ++i) a8[i] += a8[i + 4];              \
    float ps = (a8[0] + a8[1]) + (a8[2] + a8[3]);                                  \
    ps += __shfl_xor(ps, 32, 64);                                                  \
    l += ps;                                                                       \
    bf16x8 pa = make_pa(s[0], s[1], s[2], s[3], s[4], s[5], s[6], s[7]);           \
    o0 = __builtin_amdgcn_mfma_f32_32x32x16_bf16(pa, vf[0][0], o0, 0, 0, 0);       \
    o1 = __builtin_amdgcn_mfma_f32_32x32x16_bf16(pa, vf[0][1], o1, 0, 0, 0);       \
    pa = make_pa(s[8], s[9], s[10], s[11], s[12], s[13], s[14], s[15]);            \
    o0 = __builtin_amdgcn_mfma_f32_32x32x16_bf16(pa, vf[1][0], o0, 0, 0, 0);       \
    o1 = __builtin_amdgcn_mfma_f32_32x32x16_bf16(pa, vf[1][1], o1, 0, 0, 0);       \
  } while (0)

  bf16x8 kA[4], kB[4], vA[2][2], vB[2][2];
  LOADK(kA, 0);
  for (int kv0 = 0; kv0 < L_SEQ; kv0 += 64) {
    LOADV(vA, kv0);            // consumed after softmax (~300 cyc of cover)
    LOADK(kB, kv0 + 32);       // consumed next half-iter
    BODY(kA, vA);
    LOADV(vB, kv0 + 32);
    int nx = (kv0 + 64 > L_SEQ - 32) ? (L_SEQ - 32) : (kv0 + 64);
    LOADK(kA, nx);             // consumed next iter
    BODY(kB, vB);
  }
#undef LOADK
#undef LOADV
#undef BODY

  // normalize + store O as [B, L, H*64] bf16
  const int b = bh >> 4, h = bh & 15;
  float linv = 1.f / l;
#pragma unroll
  for (int r = 0; r < 16; ++r) {
    int ql = (r & 3) + 8 * (r >> 2) + 4 * hi;
    float li = __shfl(linv, ql, 64);
    size_t base = ((size_t)b * L_SEQ + qw + ql) * DMODEL + h * 64 + r31;
    O[base] = (__bf16)(o0[r] * li);
    O[base + 32] = (__bf16)(o1[r] * li);
  }
}

extern "C" void kernel_launch(void* const* d_in, const int* in_sizes, int n_in,
                              void* d_out, int out_size, void* d_ws, size_t ws_size,
                              hipStream_t stream) {
  const float* x = (const float*)d_in[0];
  const float* Wqkv = (const float*)d_in[1];
  const float* bqkv = (const float*)d_in[2];
  const float* Wout = (const float*)d_in[3];
  const float* bout = (const float*)d_in[4];
  float* out = (float*)d_out;

  char* ws = (char*)d_ws;
  __bf16* Xb    = (__bf16*)(ws + 0);
  __bf16* Wqkvt = (__bf16*)(ws + 16777216);
  __bf16* Woutt = (__bf16*)(ws + 23068672);
  __bf16* Qb    = (__bf16*)(ws + 25165824);
  __bf16* Kb    = (__bf16*)(ws + 41943040);
  __bf16* Vtb   = (__bf16*)(ws + 58720256);
  __bf16* Ob    = (__bf16*)(ws + 0);  // reuse Xb region after GEMM1

  k_convert_x<<<8192, 256, 0, stream>>>(x, Xb);
  k_transpose_bf16<<<dim3(96, 32), dim3(32, 8), 0, stream>>>(Wqkv, Wqkvt, 1024, 3072);
  k_transpose_bf16<<<dim3(32, 32), dim3(32, 8), 0, stream>>>(Wout, Woutt, 1024, 1024);
  k_gemm<0><<<dim3(24, 64), 256, 0, stream>>>(Xb, Wqkvt, bqkv, nullptr, Qb, Kb, Vtb,
                                              8192, 3072, 1024);
  k_attn<<<dim3(1024), 256, 0, stream>>>(Qb, Kb, Vtb, Ob);
  k_gemm<1><<<dim3(8, 64), 256, 0, stream>>>(Ob, Woutt, bout, out, nullptr, nullptr, nullptr,
                                             8192, 1024, 1024);
}